// Round 13
// baseline (42.420 us; speedup 1.0000x reference)
//
#include <hip/hip_runtime.h>
#include <math.h>

#define NPV 3072
#define LDP 3073
#define EPSF 1e-8f
#define NMOM 52        // [0..6] w-moments, [7..51] 45-entry sym tensor
#define NSEG 64        // row segments (48 rows each)
#define NCHUNK 12      // column chunks (256 cols each)
#define NTILE (NSEG * NCHUNK)  // 768 tile blocks
#define NMOMBLK 12     // rowmom blocks
#define NPART (NMOMBLK * 4)    // 48 moment partials

// Branchless insert of v into sorted-descending triple: 3 ops, depth-1 chain.
// na = max(a,v); nb = median(a,b,v); nc = median(b,c,v).
#define INS3(v, a, b, c) do { \
    float _v = (v); \
    float _na = fmaxf((a), _v); \
    float _nb = __builtin_amdgcn_fmed3f((a), (b), _v); \
    float _nc = __builtin_amdgcn_fmed3f((b), (c), _v); \
    (a) = _na; (b) = _nb; (c) = _nc; } while (0)

#define MRG3(x, y, z, a, b, c) do { \
    INS3((x), a, b, c); INS3((y), a, b, c); INS3((z), a, b, c); } while (0)

// Branchless insert of (v,j) into descending (a,ja)>=(b,jb)>=(c,jc).
#define INSJ(v, j, a, ja, b, jb, c, jc) do { \
    bool _g1 = (v) > (a); \
    bool _g2 = (v) > (b); \
    bool _g3 = (v) > (c); \
    float _nc = _g2 ? (b) : (_g3 ? (v) : (c)); \
    int  _njc = _g2 ? (jb) : (_g3 ? (j) : (jc)); \
    float _nb = _g1 ? (a) : (_g2 ? (v) : (b)); \
    int  _njb = _g1 ? (ja) : (_g2 ? (j) : (jb)); \
    (a) = _g1 ? (v) : (a); \
    (ja) = _g1 ? (j) : (ja); \
    (b) = _nb; (jb) = _njb; \
    (c) = _nc; (jc) = _njc; } while (0)

__device__ __forceinline__ void kinv6(const float* __restrict__ Kmat,
        float& ki0, float& ki1, float& ki2, float& ki3, float& ki4, float& ki5)
{
    float k00 = Kmat[0], k01 = Kmat[1], k02 = Kmat[2];
    float k10 = Kmat[3], k11 = Kmat[4], k12 = Kmat[5];
    float k20 = Kmat[6], k21 = Kmat[7], k22 = Kmat[8];
    float det = k00 * (k11 * k22 - k12 * k21) - k01 * (k10 * k22 - k12 * k20) + k02 * (k10 * k21 - k11 * k20);
    float id = 1.0f / det;
    ki0 = (k11 * k22 - k12 * k21) * id; ki1 = (k02 * k21 - k01 * k22) * id; ki2 = (k01 * k12 - k02 * k11) * id;
    ki3 = (k12 * k20 - k10 * k22) * id; ki4 = (k00 * k22 - k02 * k20) * id; ki5 = (k02 * k10 - k00 * k12) * id;
}

// ======== Kernel 1: single pass over P. Col-top3 partials (registers) +
// row-chunk top-3 via values-only scan + rare extraction. grid = 768 x 256. ==
__global__ __launch_bounds__(256) void k_tile(const float* __restrict__ P,
        float4* __restrict__ part, float* __restrict__ rpv, int* __restrict__ rpj)
{
    __shared__ float lds[48][257];
    __shared__ int   scnt[48];
    __shared__ int   sjs[48][4];
    __shared__ float svs[48][4];
    int t = threadIdx.x;
    int chunk = blockIdx.x % NCHUNK;
    int seg   = blockIdx.x / NCHUNK;
    int j0 = chunk * 256;
    int i0 = seg * 48;
    const float* base = P + (size_t)i0 * LDP + j0 + t;

    if (t < 48) scnt[t] = 0;

    float a0 = -1e30f, b0 = -1e30f, c0 = -1e30f;
    float a1 = -1e30f, b1 = -1e30f, c1 = -1e30f;
    float a2 = -1e30f, b2 = -1e30f, c2 = -1e30f;
    float a3 = -1e30f, b3 = -1e30f, c3v = -1e30f;
    float a4 = -1e30f, b4 = -1e30f, c4 = -1e30f;
    float a5 = -1e30f, b5 = -1e30f, c5 = -1e30f;
    float a6 = -1e30f, b6 = -1e30f, c6 = -1e30f;
    float a7 = -1e30f, b7 = -1e30f, c7 = -1e30f;
    #pragma unroll
    for (int r = 0; r < 48; r += 8) {
        float v0 = base[(size_t)(r + 0) * LDP];
        float v1 = base[(size_t)(r + 1) * LDP];
        float v2 = base[(size_t)(r + 2) * LDP];
        float v3 = base[(size_t)(r + 3) * LDP];
        float v4 = base[(size_t)(r + 4) * LDP];
        float v5 = base[(size_t)(r + 5) * LDP];
        float v6 = base[(size_t)(r + 6) * LDP];
        float v7 = base[(size_t)(r + 7) * LDP];
        lds[r + 0][t] = v0;
        lds[r + 1][t] = v1;
        lds[r + 2][t] = v2;
        lds[r + 3][t] = v3;
        lds[r + 4][t] = v4;
        lds[r + 5][t] = v5;
        lds[r + 6][t] = v6;
        lds[r + 7][t] = v7;
        INS3(v0, a0, b0, c0);
        INS3(v1, a1, b1, c1);
        INS3(v2, a2, b2, c2);
        INS3(v3, a3, b3, c3v);
        INS3(v4, a4, b4, c4);
        INS3(v5, a5, b5, c5);
        INS3(v6, a6, b6, c6);
        INS3(v7, a7, b7, c7);
    }
    MRG3(a1, b1, c1, a0, b0, c0);
    MRG3(a2, b2, c2, a0, b0, c0);
    MRG3(a3, b3, c3v, a0, b0, c0);
    MRG3(a4, b4, c4, a0, b0, c0);
    MRG3(a5, b5, c5, a0, b0, c0);
    MRG3(a6, b6, c6, a0, b0, c0);
    MRG3(a7, b7, c7, a0, b0, c0);
    part[(size_t)seg * NPV + j0 + t] = make_float4(a0, b0, c0, 0.f);

    __syncthreads();

    // Row phase: thread = row*4 + sub. Pass 1: values-only top-3 of the 64-col
    // subsegment (3 ops/elem, depth-1); shfl merge across the 4 subs -> c3.
    // Pass 2: extract the exactly-3 entries >= c3 via rare LDS-atomic append.
    if (t < 192) {
        int row = t >> 2, sub = t & 3;
        int cbase = sub * 64;
        int rot = (sub & 1) << 4;   // stagger: 2-way bank alias = free
        float A = -1e30f, B = -1e30f, C = -1e30f;
        #pragma unroll 8
        for (int s = 0; s < 64; ++s) {
            int idx = (s + rot) & 63;
            float v = lds[row][cbase + idx];
            INS3(v, A, B, C);
        }
        #pragma unroll
        for (int off = 1; off <= 2; off <<= 1) {
            float xa = __shfl_xor(A, off);
            float xb = __shfl_xor(B, off);
            float xc = __shfl_xor(C, off);
            MRG3(xa, xb, xc, A, B, C);
        }
        float c3 = C;   // row-chunk 3rd-largest, uniform across the 4 subs
        #pragma unroll 8
        for (int s = 0; s < 64; ++s) {
            int idx = (s + rot) & 63;
            float v = lds[row][cbase + idx];
            if (v >= c3) {
                int p = atomicAdd(&scnt[row], 1);
                if (p < 4) { sjs[row][p] = j0 + cbase + idx; svs[row][p] = v; }
            }
        }
    }
    __syncthreads();
    if (t < 48) {
        int n = scnt[t]; n = n > 3 ? 3 : n;
        int i = i0 + t;
        #pragma unroll
        for (int k = 0; k < 3; ++k) {
            bool ok = k < n;
            rpv[(size_t)(chunk * 3 + k) * NPV + i] = ok ? svs[t][k] : -1e30f;
            rpj[(size_t)(chunk * 3 + k) * NPV + i] = ok ? sjs[t][k] : 0;
        }
    }
}

// ======== Kernel 2: merge col partials -> tc. Also zeroes the ticket. ======
__global__ __launch_bounds__(256) void k_colmerge(const float4* __restrict__ part,
        float* __restrict__ tc, int* __restrict__ ticket)
{
    if (blockIdx.x == 0 && threadIdx.x == 0) *ticket = 0;
    int sub = threadIdx.x & 15;
    int j = blockIdx.x * 16 + (threadIdx.x >> 4);
    float4 buf[NSEG / 16];
    #pragma unroll
    for (int k = 0; k < NSEG / 16; ++k)
        buf[k] = part[(size_t)(sub + (k << 4)) * NPV + j];
    float a = -1e30f, b = -1e30f, c = -1e30f;
    #pragma unroll
    for (int k = 0; k < NSEG / 16; ++k) MRG3(buf[k].x, buf[k].y, buf[k].z, a, b, c);
    #pragma unroll
    for (int off = 1; off < 16; off <<= 1) {
        float xa = __shfl_xor(a, off);
        float xb = __shfl_xor(b, off);
        float xc = __shfl_xor(c, off);
        MRG3(xa, xb, xc, a, b, c);
    }
    if (sub == 0) tc[j] = c;
}

// ---------------- moments + tail helpers ------------------------------------
__device__ __forceinline__ void acc_pair(float* m, float w, float xs1, float ys1,
                                         float xs2, float ys2)
{
    m[0] += w;
    m[1] += w * xs1; m[2] += w * ys1; m[3] += w * (xs1 * xs1 + ys1 * ys1);
    m[4] += w * xs2; m[5] += w * ys2; m[6] += w * (xs2 * xs2 + ys2 * ys2);
    float a[9] = { xs1 * xs2, xs1 * ys2, xs1, ys1 * xs2, ys1 * ys2, ys1, xs2, ys2, 1.f };
    int idx = 7;
    #pragma unroll
    for (int u = 0; u < 9; ++u) {
        float wa = w * a[u];
        #pragma unroll
        for (int v = u; v < 9; ++v) { m[idx] = fmaf(wa, a[v], m[idx]); ++idx; }
    }
}

__device__ __forceinline__ void mm3r(const float* A, const float* B, float* C) {
    #pragma unroll
    for (int r = 0; r < 3; ++r)
        #pragma unroll
        for (int c = 0; c < 3; ++c)
            C[r * 3 + c] = A[r * 3 + 0] * B[0 + c] + A[r * 3 + 1] * B[3 + c] + A[r * 3 + 2] * B[6 + c];
}

__device__ __forceinline__ float det3(const float* M) {
    return M[0] * (M[4] * M[8] - M[5] * M[7])
         - M[1] * (M[3] * M[8] - M[5] * M[6])
         + M[2] * (M[3] * M[7] - M[4] * M[6]);
}

__device__ void ph_tail(const float* __restrict__ Kmat,
        const float* __restrict__ momp, float* __restrict__ out, int t)
{
    __shared__ float sMom[NMOM];
    __shared__ float sM[81], sY[81], sP[81], sT[81];
    __shared__ float sT1[9], sT2[9];

    if (t < NMOM) {
        float s = 0.f;
        #pragma unroll 8
        for (int b = 0; b < NPART; ++b) s += momp[(size_t)b * 64 + t];
        sMom[t] = s;
    }
    __syncthreads();

    float ki0, ki1, ki2, ki3, ki4, ki5;
    kinv6(Kmat, ki0, ki1, ki2, ki3, ki4, ki5);
    float u0x = ki0 * 31.5f + ki1 * 23.5f + ki2;
    float u0y = ki3 * 31.5f + ki4 * 23.5f + ki5;

    float Sw = sMom[0];
    float ws = Sw + EPSF;
    float c1x = sMom[1] / ws, c1y = sMom[2] / ws;
    float c2x = sMom[4] / ws, c2y = sMom[5] / ws;
    float q1 = (sMom[3] - 2.f * (c1x * sMom[1] + c1y * sMom[2]) + (c1x * c1x + c1y * c1y) * Sw) / ws;
    float q2 = (sMom[6] - 2.f * (c2x * sMom[4] + c2y * sMom[5]) + (c2x * c2x + c2y * c2y) * Sw) / ws;
    float md1 = sqrtf(fmaxf(q1, 0.f) + EPSF);
    float md2 = sqrtf(fmaxf(q2, 0.f) + EPSF);
    float s1 = 1.4142135623730951f / (md1 + EPSF);
    float s2 = 1.4142135623730951f / (md2 + EPSF);

    if (t < 81) {
        int r = t / 9, c = t % 9;
        int u = r < c ? r : c, v = r < c ? c : r;
        int idx = 7 + u * 9 - (u * (u + 1)) / 2 + v;
        sM[t] = sMom[idx];
    }
    if (t == 0) {
        sT1[0] = s1; sT1[1] = 0.f; sT1[2] = -s1 * c1x;
        sT1[3] = 0.f; sT1[4] = s1; sT1[5] = -s1 * c1y;
        sT1[6] = 0.f; sT1[7] = 0.f; sT1[8] = 1.f;
        sT2[0] = s2; sT2[1] = 0.f; sT2[2] = -s2 * c2x;
        sT2[3] = 0.f; sT2[4] = s2; sT2[5] = -s2 * c2y;
        sT2[6] = 0.f; sT2[7] = 0.f; sT2[8] = 1.f;
    }
    __syncthreads();

    if (t < 81) {
        int k = t / 9, c = t % 9;
        float s = 0.f;
        #pragma unroll
        for (int l = 0; l < 9; ++l)
            s = fmaf(sM[k * 9 + l], sT1[(c / 3) * 3 + (l / 3)] * sT2[(c % 3) * 3 + (l % 3)], s);
        sY[t] = s;
    }
    __syncthreads();
    if (t < 81) {
        int r = t / 9, c = t % 9;
        float s = 0.f;
        #pragma unroll
        for (int k = 0; k < 9; ++k)
            s = fmaf(sT1[(r / 3) * 3 + (k / 3)] * sT2[(r % 3) * 3 + (k % 3)], sY[k * 9 + c], s);
        sP[t] = s;
    }
    __syncthreads();
    if (t < 81) {
        int r = t / 9, c = t % 9;
        float lam = sP[0] + sP[10] + sP[20] + sP[30] + sP[40] + sP[50] + sP[60] + sP[70] + sP[80];
        float il = 1.f / (lam + 1e-30f);
        sM[t] = ((r == c ? lam : 0.f) - sP[t]) * il;
    }
    __syncthreads();

#define MM81(DST, A, B) \
    if (t < 81) { \
        int _r = t / 9, _c = t % 9; \
        float _s = 0.f; \
        _Pragma("unroll") \
        for (int _k = 0; _k < 9; ++_k) _s = fmaf(A[_r * 9 + _k], B[_k * 9 + _c], _s); \
        DST[t] = _s; \
    } \
    __syncthreads();

    MM81(sY, sM, sM)   // P2   (kept)
    MM81(sP, sY, sY)   // P4
    MM81(sT, sP, sP)   // P8
    MM81(sP, sT, sT)   // P16  (kept)
    MM81(sT, sP, sP)   // P32
    MM81(sM, sT, sP)   // R  = P32*P16
    MM81(sT, sM, sY)   // P50 = R*P2
#undef MM81

    if (t < 64) {
        float v9[9];
        float nrm = 0.f;
        #pragma unroll
        for (int r = 0; r < 9; ++r) {
            float s = 0.f;
            #pragma unroll
            for (int c = 0; c < 9; ++c) s += sT[r * 9 + c];
            v9[r] = s * (1.f / 3.f);
            nrm += v9[r] * v9[r];
        }
        nrm = sqrtf(nrm) + EPSF;
        #pragma unroll
        for (int r = 0; r < 9; ++r) v9[r] /= nrm;

        float C1x = c1x + u0x, C1y = c1y + u0y;
        float C2x = c2x + u0x, C2y = c2y + u0y;
        float T1f[9] = { s1, 0.f, -s1 * C1x, 0.f, s1, -s1 * C1y, 0.f, 0.f, 1.f };
        float T2t[9] = { s2, 0.f, 0.f, 0.f, s2, 0.f, -s2 * C2x, -s2 * C2y, 1.f };
        float M1[9], Ee[9];
        mm3r(v9, T1f, M1);
        mm3r(T2t, M1, Ee);

        float B[9];
        #pragma unroll
        for (int r = 0; r < 3; ++r)
            #pragma unroll
            for (int c = 0; c < 3; ++c)
                B[r * 3 + c] = Ee[r] * Ee[c] + Ee[3 + r] * Ee[3 + c] + Ee[6 + r] * Ee[6 + c];
        float lam3 = B[0] + B[4] + B[8];
        float il3 = 1.f / (lam3 + 1e-30f);

        int parity = t & 1;
        float P1[9];
        #pragma unroll
        for (int k = 0; k < 9; ++k) {
            float d = (k == 0 || k == 4 || k == 8) ? lam3 : 0.f;
            P1[k] = (parity ? (d - B[k]) : B[k]) * il3;
        }
        float P2[9], P4[9], P8[9], P16[9], P32[9], R1[9], P50[9];
        mm3r(P1, P1, P2);
        mm3r(P2, P2, P4);
        mm3r(P4, P4, P8);
        mm3r(P8, P8, P16);
        mm3r(P16, P16, P32);
        mm3r(P32, P16, R1);
        mm3r(R1, P2, P50);
        float vx = (P50[0] + P50[1] + P50[2]) * 0.57735026918962584f;
        float vy = (P50[3] + P50[4] + P50[5]) * 0.57735026918962584f;
        float vz = (P50[6] + P50[7] + P50[8]) * 0.57735026918962584f;
        float vn = sqrtf(vx * vx + vy * vy + vz * vz) + EPSF;
        vx /= vn; vy /= vn; vz /= vn;

        float v3x = __shfl(vx, 1), v3y = __shfl(vy, 1), v3z = __shfl(vz, 1);

        if (t == 0) {
            float v1[3] = { vx, vy, vz };
            float v3[3] = { v3x, v3y, v3z };
            float v2[3];
            v2[0] = v3[1] * v1[2] - v3[2] * v1[1];
            v2[1] = v3[2] * v1[0] - v3[0] * v1[2];
            v2[2] = v3[0] * v1[1] - v3[1] * v1[0];
            float n2 = sqrtf(v2[0] * v2[0] + v2[1] * v2[1] + v2[2] * v2[2]) + EPSF;
            v2[0] /= n2; v2[1] /= n2; v2[2] /= n2;
            float V[9];
            #pragma unroll
            for (int r = 0; r < 3; ++r) { V[r * 3 + 0] = v1[r]; V[r * 3 + 1] = v2[r]; V[r * 3 + 2] = v3[r]; }
            float dV = det3(V);
            float sV = (dV > 0.f) ? 1.f : ((dV < 0.f) ? -1.f : 0.f);
            V[2] *= sV; V[5] *= sV; V[8] *= sV;
            float Ev1[3], Ev2[3];
            #pragma unroll
            for (int r = 0; r < 3; ++r) {
                Ev1[r] = Ee[r * 3] * V[0] + Ee[r * 3 + 1] * V[3] + Ee[r * 3 + 2] * V[6];
                Ev2[r] = Ee[r * 3] * V[1] + Ee[r * 3 + 1] * V[4] + Ee[r * 3 + 2] * V[7];
            }
            float s1n = sqrtf(Ev1[0] * Ev1[0] + Ev1[1] * Ev1[1] + Ev1[2] * Ev1[2]);
            float s2n = sqrtf(Ev2[0] * Ev2[0] + Ev2[1] * Ev2[1] + Ev2[2] * Ev2[2]);
            float s_avg = (s1n + s2n) * 0.5f;
            float u1[3], u2[3];
            #pragma unroll
            for (int r = 0; r < 3; ++r) { u1[r] = Ev1[r] / (s1n + EPSF); u2[r] = Ev2[r] / (s2n + EPSF); }
            #pragma unroll
            for (int r = 0; r < 3; ++r)
                #pragma unroll
                for (int c = 0; c < 3; ++c)
                    out[r * 3 + c] = s_avg * (u1[r] * V[c * 3 + 0] + u2[r] * V[c * 3 + 1]);
        }
    }
}

// ======== Kernel 3: merge row-chunk top-3s, filter, moments; last block
// (ticket, fence) runs the tail. grid = 12 x 256. =============================
__global__ __launch_bounds__(256) void k_rowmom(const float* __restrict__ Kmat,
        const float* __restrict__ tc, const float* __restrict__ rpv,
        const int* __restrict__ rpj, float* __restrict__ momp,
        int* __restrict__ ticket, float* __restrict__ out)
{
    __shared__ int slast;
    int t = threadIdx.x;
    int i = blockIdx.x * 256 + t;

    float A = -1e30f, B = -1e30f, C = -1e30f;
    int JA = 0, JB = 0, JC = 0;
    #pragma unroll
    for (int ch = 0; ch < NCHUNK; ++ch) {
        #pragma unroll
        for (int k = 0; k < 3; ++k) {
            float v = rpv[(size_t)(ch * 3 + k) * NPV + i];
            int   j = rpj[(size_t)(ch * 3 + k) * NPV + i];
            INSJ(v, j, A, JA, B, JB, C, JC);
        }
    }

    // Sort the 3 candidates ascending-j (matches jnp summation order).
#define CSWJ(jx, vx, jy, vy) do { \
        bool _sw = (jx) > (jy); \
        float _tv = _sw ? (vx) : (vy); \
        int   _tj = _sw ? (jx) : (jy); \
        (vx) = _sw ? (vy) : (vx); (jx) = _sw ? (jy) : (jx); \
        (vy) = _tv; (jy) = _tj; } while (0)
    CSWJ(JA, A, JB, B);
    CSWJ(JB, B, JC, C);
    CSWJ(JA, A, JB, B);
#undef CSWJ

    float ki0, ki1, ki2, ki3, ki4, ki5;
    kinv6(Kmat, ki0, ki1, ki2, ki3, ki4, ki5);
    float m[NMOM];
    #pragma unroll
    for (int k = 0; k < NMOM; ++k) m[k] = 0.f;
    float xg = (float)(i & 63) - 31.5f, yg = (float)(i >> 6) - 23.5f;
    float xs1 = ki0 * xg + ki1 * yg;
    float ys1 = ki3 * xg + ki4 * yg;
#define ACCJ(V, J) do { \
    if ((V) > 0.01f && (V) >= tc[J]) { \
        float _xg = (float)((J) & 63) - 31.5f, _yg = (float)((J) >> 6) - 23.5f; \
        float xs2 = ki0 * _xg + ki1 * _yg; \
        float ys2 = ki3 * _xg + ki4 * _yg; \
        acc_pair(m, (V), xs1, ys1, xs2, ys2); \
    } } while (0)
    ACCJ(A, JA);
    ACCJ(B, JB);
    ACCJ(C, JC);
#undef ACCJ

    #pragma unroll
    for (int k = 0; k < NMOM; ++k) {
        #pragma unroll
        for (int off = 32; off; off >>= 1) m[k] += __shfl_xor(m[k], off);
    }
    int lane = t & 63, wid = t >> 6;
    if (lane == 0) {
        float* dst = momp + (size_t)(blockIdx.x * 4 + wid) * 64;
        #pragma unroll
        for (int k = 0; k < NMOM; ++k) dst[k] = m[k];
    }

    __threadfence();
    __syncthreads();
    if (t == 0) slast = (atomicAdd(ticket, 1) == NMOMBLK - 1) ? 1 : 0;
    __syncthreads();
    if (!slast) return;
    __threadfence();
    ph_tail(Kmat, momp, out, t);
}

extern "C" void kernel_launch(void* const* d_in, const int* in_sizes, int n_in,
                              void* d_out, int out_size, void* d_ws, size_t ws_size,
                              hipStream_t stream)
{
    const float* P = (const float*)d_in[0];
    const float* K = (const float*)d_in[1];
    float* out = (float*)d_out;

    float* fws   = (float*)d_ws;
    float* tc    = fws;                            // 3072
    float* rpv   = tc + NPV;                       // 36*3072
    int*   rpj   = (int*)(rpv + 36 * NPV);         // 36*3072
    float* momp  = (float*)(rpj + 36 * NPV);       // 48*64
    int*   ticket = (int*)(momp + NPART * 64);     // 16 ints pad
    float4* part = (float4*)(ticket + 16);         // 64*3072 float4

    k_tile    <<<NTILE, 256, 0, stream>>>(P, part, rpv, rpj);
    k_colmerge<<<NPV / 16, 256, 0, stream>>>(part, tc, ticket);
    k_rowmom  <<<NMOMBLK, 256, 0, stream>>>(K, tc, rpv, rpj, momp, ticket, out);
}

// Round 14
// 40.041 us; speedup vs baseline: 1.0594x; 1.0594x over previous
//
#include <hip/hip_runtime.h>
#include <math.h>

#define NPV 3072
#define LDP 3073
#define EPSF 1e-8f
#define NMOM 52   // [0..6] w-moments (Sw, Sx1,Sy1,Sq1, Sx2,Sy2,Sq2), [7..51] 45 sym tensor
#define NROWBLK (NPV / 64)   // 48 moment blocks

// Branchless insert of v into sorted-descending triple (a >= b >= c).
#define INS3(v, a, b, c) do { \
    float _m1 = fminf((a), (v)); (a) = fmaxf((a), (v)); \
    float _m2 = fminf((b), _m1); (b) = fmaxf((b), _m1); \
    (c) = fmaxf((c), _m2); } while (0)

#define MRG3(x, y, z, a, b, c) do { \
    INS3((x), a, b, c); INS3((y), a, b, c); INS3((z), a, b, c); } while (0)

__device__ __forceinline__ void kinv6(const float* __restrict__ Kmat,
        float& ki0, float& ki1, float& ki2, float& ki3, float& ki4, float& ki5)
{
    float k00 = Kmat[0], k01 = Kmat[1], k02 = Kmat[2];
    float k10 = Kmat[3], k11 = Kmat[4], k12 = Kmat[5];
    float k20 = Kmat[6], k21 = Kmat[7], k22 = Kmat[8];
    float det = k00 * (k11 * k22 - k12 * k21) - k01 * (k10 * k22 - k12 * k20) + k02 * (k10 * k21 - k11 * k20);
    float id = 1.0f / det;
    ki0 = (k11 * k22 - k12 * k21) * id; ki1 = (k02 * k21 - k01 * k22) * id; ki2 = (k01 * k12 - k02 * k11) * id;
    ki3 = (k12 * k20 - k10 * k22) * id; ki4 = (k00 * k22 - k02 * k20) * id; ki5 = (k02 * k10 - k00 * k12) * id;
}

// One wave per row (4 rows/block), branchless values-only top-3.
__global__ __launch_bounds__(256) void k_row_top3(const float* __restrict__ P,
        float* __restrict__ tr, int* __restrict__ rowcnt)
{
    int lane = threadIdx.x & 63;
    int i = blockIdx.x * 4 + (threadIdx.x >> 6);
    const float* row = P + (size_t)i * LDP;
    float a0 = -1e30f, b0 = -1e30f, c0 = -1e30f;
    float a1 = -1e30f, b1 = -1e30f, c1 = -1e30f;
    float a2 = -1e30f, b2 = -1e30f, c2 = -1e30f;
    float a3 = -1e30f, b3 = -1e30f, c3 = -1e30f;
    #pragma unroll
    for (int r = 0; r < 48; r += 4) {
        float v0 = row[(r + 0) * 64 + lane];
        float v1 = row[(r + 1) * 64 + lane];
        float v2 = row[(r + 2) * 64 + lane];
        float v3 = row[(r + 3) * 64 + lane];
        INS3(v0, a0, b0, c0);
        INS3(v1, a1, b1, c1);
        INS3(v2, a2, b2, c2);
        INS3(v3, a3, b3, c3);
    }
    MRG3(a1, b1, c1, a0, b0, c0);
    MRG3(a2, b2, c2, a0, b0, c0);
    MRG3(a3, b3, c3, a0, b0, c0);
    #pragma unroll
    for (int off = 1; off < 64; off <<= 1) {
        float xa = __shfl_xor(a0, off);
        float xb = __shfl_xor(b0, off);
        float xc = __shfl_xor(c0, off);
        MRG3(xa, xb, xc, a0, b0, c0);
    }
    if (lane == 0) { tr[i] = c0; rowcnt[i] = 0; }
}

#define CAND(v, i) do { \
    if ((v) >= tr[i] && (v) > 0.01f) { \
        int _s = atomicAdd(&rowcnt[i], 1); \
        if (_s < 8) { rowj[(size_t)(i) * 8 + _s] = j; roww[(size_t)(i) * 8 + _s] = (v); } \
    } } while (0)

__global__ __launch_bounds__(256) void k_col_pass(const float* __restrict__ P,
        const float* __restrict__ tr, float4* __restrict__ part, int segrows,
        int* __restrict__ rowcnt, int* __restrict__ rowj, float* __restrict__ roww)
{
    int j = blockIdx.x * 256 + threadIdx.x;
    int i0 = blockIdx.y * segrows;
    float a0 = -1e30f, b0 = -1e30f, c0 = -1e30f;
    float a1 = -1e30f, b1 = -1e30f, c1 = -1e30f;
    float a2 = -1e30f, b2 = -1e30f, c2 = -1e30f;
    float a3 = -1e30f, b3 = -1e30f, c3 = -1e30f;
    float a4 = -1e30f, b4 = -1e30f, c4 = -1e30f;
    float a5 = -1e30f, b5 = -1e30f, c5 = -1e30f;
    float a6 = -1e30f, b6 = -1e30f, c6 = -1e30f;
    float a7 = -1e30f, b7 = -1e30f, c7 = -1e30f;
    for (int r = 0; r < segrows; r += 8) {
        int i = i0 + r;
        const float* col = P + (size_t)i * LDP + j;
        float v0 = col[0 * LDP];
        float v1 = col[1 * LDP];
        float v2 = col[2 * LDP];
        float v3 = col[3 * LDP];
        float v4 = col[4 * LDP];
        float v5 = col[5 * LDP];
        float v6 = col[6 * LDP];
        float v7 = col[7 * LDP];
        INS3(v0, a0, b0, c0);
        INS3(v1, a1, b1, c1);
        INS3(v2, a2, b2, c2);
        INS3(v3, a3, b3, c3);
        INS3(v4, a4, b4, c4);
        INS3(v5, a5, b5, c5);
        INS3(v6, a6, b6, c6);
        INS3(v7, a7, b7, c7);
        CAND(v0, i + 0);
        CAND(v1, i + 1);
        CAND(v2, i + 2);
        CAND(v3, i + 3);
        CAND(v4, i + 4);
        CAND(v5, i + 5);
        CAND(v6, i + 6);
        CAND(v7, i + 7);
    }
    MRG3(a1, b1, c1, a0, b0, c0);
    MRG3(a2, b2, c2, a0, b0, c0);
    MRG3(a3, b3, c3, a0, b0, c0);
    MRG3(a4, b4, c4, a0, b0, c0);
    MRG3(a5, b5, c5, a0, b0, c0);
    MRG3(a6, b6, c6, a0, b0, c0);
    MRG3(a7, b7, c7, a0, b0, c0);
    part[(size_t)blockIdx.y * NPV + j] = make_float4(a0, b0, c0, 0.f);
}

// 16 threads per column, NSEG/16 segments each, 4-step shfl merge.
// Block 0 thread 0 also zeroes the ticket for the fused moments+tail kernel.
template<int NSEG>
__global__ __launch_bounds__(256) void k_col_merge(const float4* __restrict__ part,
        float* __restrict__ tc, int* __restrict__ ticket)
{
    if (blockIdx.x == 0 && threadIdx.x == 0) *ticket = 0;
    int sub = threadIdx.x & 15;
    int j = blockIdx.x * 16 + (threadIdx.x >> 4);
    constexpr int CNT = NSEG / 16;
    float4 buf[CNT];
    #pragma unroll
    for (int k = 0; k < CNT; ++k)
        buf[k] = part[(size_t)(sub + (k << 4)) * NPV + j];
    float a = -1e30f, b = -1e30f, c = -1e30f;
    #pragma unroll
    for (int k = 0; k < CNT; ++k) MRG3(buf[k].x, buf[k].y, buf[k].z, a, b, c);
    #pragma unroll
    for (int off = 1; off < 16; off <<= 1) {
        float xa = __shfl_xor(a, off);
        float xb = __shfl_xor(b, off);
        float xc = __shfl_xor(c, off);
        MRG3(xa, xb, xc, a, b, c);
    }
    if (sub == 0) tc[j] = c;
}

// Accumulate per-candidate contribution to the 52 moments (mean-shifted coords).
__device__ __forceinline__ void acc_pair(float* m, float w, float xs1, float ys1,
                                         float xs2, float ys2)
{
    m[0] += w;
    m[1] += w * xs1; m[2] += w * ys1; m[3] += w * (xs1 * xs1 + ys1 * ys1);
    m[4] += w * xs2; m[5] += w * ys2; m[6] += w * (xs2 * xs2 + ys2 * ys2);
    float a[9] = { xs1 * xs2, xs1 * ys2, xs1, ys1 * xs2, ys1 * ys2, ys1, xs2, ys2, 1.f };
    int idx = 7;
    #pragma unroll
    for (int u = 0; u < 9; ++u) {
        float wa = w * a[u];
        #pragma unroll
        for (int v = u; v < 9; ++v) { m[idx] = fmaf(wa, a[v], m[idx]); ++idx; }
    }
}

__device__ __forceinline__ void mm3r(const float* A, const float* B, float* C) {
    #pragma unroll
    for (int r = 0; r < 3; ++r)
        #pragma unroll
        for (int c = 0; c < 3; ++c)
            C[r * 3 + c] = A[r * 3 + 0] * B[0 + c] + A[r * 3 + 1] * B[3 + c] + A[r * 3 + 2] * B[6 + c];
}

__device__ __forceinline__ float det3(const float* M) {
    return M[0] * (M[4] * M[8] - M[5] * M[7])
         - M[1] * (M[3] * M[8] - M[5] * M[6])
         + M[2] * (M[3] * M[7] - M[4] * M[6]);
}

// Tail: partial-reduce + congruence transform + matrix-power chains. 128 thr.
__device__ void ph_tail(const float* __restrict__ Kmat,
        const float* __restrict__ momp, float* __restrict__ out, int t)
{
    __shared__ float sMom[NMOM];
    __shared__ float sM[81], sY[81], sP[81], sT[81];
    __shared__ float sT1[9], sT2[9];

    if (t < NMOM) {
        float s = 0.f;
        #pragma unroll 8
        for (int b = 0; b < NROWBLK; ++b) s += momp[(size_t)b * 64 + t];
        sMom[t] = s;
    }
    __syncthreads();

    float ki0, ki1, ki2, ki3, ki4, ki5;
    kinv6(Kmat, ki0, ki1, ki2, ki3, ki4, ki5);
    float u0x = ki0 * 31.5f + ki1 * 23.5f + ki2;
    float u0y = ki3 * 31.5f + ki4 * 23.5f + ki5;

    float Sw = sMom[0];
    float ws = Sw + EPSF;
    float c1x = sMom[1] / ws, c1y = sMom[2] / ws;
    float c2x = sMom[4] / ws, c2y = sMom[5] / ws;
    float q1 = (sMom[3] - 2.f * (c1x * sMom[1] + c1y * sMom[2]) + (c1x * c1x + c1y * c1y) * Sw) / ws;
    float q2 = (sMom[6] - 2.f * (c2x * sMom[4] + c2y * sMom[5]) + (c2x * c2x + c2y * c2y) * Sw) / ws;
    float md1 = sqrtf(fmaxf(q1, 0.f) + EPSF);
    float md2 = sqrtf(fmaxf(q2, 0.f) + EPSF);
    float s1 = 1.4142135623730951f / (md1 + EPSF);
    float s2 = 1.4142135623730951f / (md2 + EPSF);

    if (t < 81) {
        int r = t / 9, c = t % 9;
        int u = r < c ? r : c, v = r < c ? c : r;
        int idx = 7 + u * 9 - (u * (u + 1)) / 2 + v;
        sM[t] = sMom[idx];
    }
    if (t == 0) {
        sT1[0] = s1; sT1[1] = 0.f; sT1[2] = -s1 * c1x;
        sT1[3] = 0.f; sT1[4] = s1; sT1[5] = -s1 * c1y;
        sT1[6] = 0.f; sT1[7] = 0.f; sT1[8] = 1.f;
        sT2[0] = s2; sT2[1] = 0.f; sT2[2] = -s2 * c2x;
        sT2[3] = 0.f; sT2[4] = s2; sT2[5] = -s2 * c2y;
        sT2[6] = 0.f; sT2[7] = 0.f; sT2[8] = 1.f;
    }
    __syncthreads();

    if (t < 81) {
        int k = t / 9, c = t % 9;
        float s = 0.f;
        #pragma unroll
        for (int l = 0; l < 9; ++l)
            s = fmaf(sM[k * 9 + l], sT1[(c / 3) * 3 + (l / 3)] * sT2[(c % 3) * 3 + (l % 3)], s);
        sY[t] = s;
    }
    __syncthreads();
    if (t < 81) {
        int r = t / 9, c = t % 9;
        float s = 0.f;
        #pragma unroll
        for (int k = 0; k < 9; ++k)
            s = fmaf(sT1[(r / 3) * 3 + (k / 3)] * sT2[(r % 3) * 3 + (k % 3)], sY[k * 9 + c], s);
        sP[t] = s;
    }
    __syncthreads();
    if (t < 81) {
        int r = t / 9, c = t % 9;
        float lam = sP[0] + sP[10] + sP[20] + sP[30] + sP[40] + sP[50] + sP[60] + sP[70] + sP[80];
        float il = 1.f / (lam + 1e-30f);
        sM[t] = ((r == c ? lam : 0.f) - sP[t]) * il;
    }
    __syncthreads();

#define MM81(DST, A, B) \
    if (t < 81) { \
        int _r = t / 9, _c = t % 9; \
        float _s = 0.f; \
        _Pragma("unroll") \
        for (int _k = 0; _k < 9; ++_k) _s = fmaf(A[_r * 9 + _k], B[_k * 9 + _c], _s); \
        DST[t] = _s; \
    } \
    __syncthreads();

    MM81(sY, sM, sM)   // P2   (kept)
    MM81(sP, sY, sY)   // P4
    MM81(sT, sP, sP)   // P8
    MM81(sP, sT, sT)   // P16  (kept)
    MM81(sT, sP, sP)   // P32
    MM81(sM, sT, sP)   // R  = P32*P16
    MM81(sT, sM, sY)   // P50 = R*P2
#undef MM81

    if (t < 64) {
        float v9[9];
        float nrm = 0.f;
        #pragma unroll
        for (int r = 0; r < 9; ++r) {
            float s = 0.f;
            #pragma unroll
            for (int c = 0; c < 9; ++c) s += sT[r * 9 + c];
            v9[r] = s * (1.f / 3.f);
            nrm += v9[r] * v9[r];
        }
        nrm = sqrtf(nrm) + EPSF;
        #pragma unroll
        for (int r = 0; r < 9; ++r) v9[r] /= nrm;

        float C1x = c1x + u0x, C1y = c1y + u0y;
        float C2x = c2x + u0x, C2y = c2y + u0y;
        float T1f[9] = { s1, 0.f, -s1 * C1x, 0.f, s1, -s1 * C1y, 0.f, 0.f, 1.f };
        float T2t[9] = { s2, 0.f, 0.f, 0.f, s2, 0.f, -s2 * C2x, -s2 * C2y, 1.f };
        float M1[9], Ee[9];
        mm3r(v9, T1f, M1);
        mm3r(T2t, M1, Ee);

        float B[9];
        #pragma unroll
        for (int r = 0; r < 3; ++r)
            #pragma unroll
            for (int c = 0; c < 3; ++c)
                B[r * 3 + c] = Ee[r] * Ee[c] + Ee[3 + r] * Ee[3 + c] + Ee[6 + r] * Ee[6 + c];
        float lam3 = B[0] + B[4] + B[8];
        float il3 = 1.f / (lam3 + 1e-30f);

        int parity = t & 1;
        float P1[9];
        #pragma unroll
        for (int k = 0; k < 9; ++k) {
            float d = (k == 0 || k == 4 || k == 8) ? lam3 : 0.f;
            P1[k] = (parity ? (d - B[k]) : B[k]) * il3;
        }
        float P2[9], P4[9], P8[9], P16[9], P32[9], R1[9], P50[9];
        mm3r(P1, P1, P2);
        mm3r(P2, P2, P4);
        mm3r(P4, P4, P8);
        mm3r(P8, P8, P16);
        mm3r(P16, P16, P32);
        mm3r(P32, P16, R1);
        mm3r(R1, P2, P50);
        float vx = (P50[0] + P50[1] + P50[2]) * 0.57735026918962584f;
        float vy = (P50[3] + P50[4] + P50[5]) * 0.57735026918962584f;
        float vz = (P50[6] + P50[7] + P50[8]) * 0.57735026918962584f;
        float vn = sqrtf(vx * vx + vy * vy + vz * vz) + EPSF;
        vx /= vn; vy /= vn; vz /= vn;

        float v3x = __shfl(vx, 1), v3y = __shfl(vy, 1), v3z = __shfl(vz, 1);

        if (t == 0) {
            float v1[3] = { vx, vy, vz };
            float v3[3] = { v3x, v3y, v3z };
            float v2[3];
            v2[0] = v3[1] * v1[2] - v3[2] * v1[1];
            v2[1] = v3[2] * v1[0] - v3[0] * v1[2];
            v2[2] = v3[0] * v1[1] - v3[1] * v1[0];
            float n2 = sqrtf(v2[0] * v2[0] + v2[1] * v2[1] + v2[2] * v2[2]) + EPSF;
            v2[0] /= n2; v2[1] /= n2; v2[2] /= n2;
            float V[9];
            #pragma unroll
            for (int r = 0; r < 3; ++r) { V[r * 3 + 0] = v1[r]; V[r * 3 + 1] = v2[r]; V[r * 3 + 2] = v3[r]; }
            float dV = det3(V);
            float sV = (dV > 0.f) ? 1.f : ((dV < 0.f) ? -1.f : 0.f);
            V[2] *= sV; V[5] *= sV; V[8] *= sV;
            float Ev1[3], Ev2[3];
            #pragma unroll
            for (int r = 0; r < 3; ++r) {
                Ev1[r] = Ee[r * 3] * V[0] + Ee[r * 3 + 1] * V[3] + Ee[r * 3 + 2] * V[6];
                Ev2[r] = Ee[r * 3] * V[1] + Ee[r * 3 + 1] * V[4] + Ee[r * 3 + 2] * V[7];
            }
            float s1n = sqrtf(Ev1[0] * Ev1[0] + Ev1[1] * Ev1[1] + Ev1[2] * Ev1[2]);
            float s2n = sqrtf(Ev2[0] * Ev2[0] + Ev2[1] * Ev2[1] + Ev2[2] * Ev2[2]);
            float s_avg = (s1n + s2n) * 0.5f;
            float u1[3], u2[3];
            #pragma unroll
            for (int r = 0; r < 3; ++r) { u1[r] = Ev1[r] / (s1n + EPSF); u2[r] = Ev2[r] / (s2n + EPSF); }
            #pragma unroll
            for (int r = 0; r < 3; ++r)
                #pragma unroll
                for (int c = 0; c < 3; ++c)
                    out[r * 3 + c] = s_avg * (u1[r] * V[c * 3 + 0] + u2[r] * V[c * 3 + 1]);
        }
    }
}

// Moments (R7's k_moments, threads 0..63) + last-ticket tail (128 threads).
__global__ __launch_bounds__(128) void k_moments_tail(const float* __restrict__ Kmat,
        const float* __restrict__ tc, const int* __restrict__ rowcnt,
        const int* __restrict__ rowj, const float* __restrict__ roww,
        float* __restrict__ momp, int* __restrict__ ticket, float* __restrict__ out)
{
    __shared__ int slast;
    int t = threadIdx.x;
    if (t < 64) {
        int i = blockIdx.x * 64 + t;
        float ki0, ki1, ki2, ki3, ki4, ki5;
        kinv6(Kmat, ki0, ki1, ki2, ki3, ki4, ki5);
        float m[NMOM];
        #pragma unroll
        for (int k = 0; k < NMOM; ++k) m[k] = 0.f;
        int n = rowcnt[i]; n = n > 8 ? 8 : n;
        const int4*   jp = (const int4*)(rowj + (size_t)i * 8);
        const float4* vp = (const float4*)(roww + (size_t)i * 8);
        int4  ja = jp[0], jb = jp[1];
        float4 va = vp[0], vb = vp[1];
        float xg = (float)(i & 63) - 31.5f, yg = (float)(i >> 6) - 23.5f;
        float xs1 = ki0 * xg + ki1 * yg;
        float ys1 = ki3 * xg + ki4 * yg;
#define ACC(S, JR, VR) do { \
        if ((S) < n) { int _j = (JR); float _w = (VR); \
            if (_w >= tc[_j]) { \
                float _xg = (float)(_j & 63) - 31.5f, _yg = (float)(_j >> 6) - 23.5f; \
                float xs2 = ki0 * _xg + ki1 * _yg; \
                float ys2 = ki3 * _xg + ki4 * _yg; \
                acc_pair(m, _w, xs1, ys1, xs2, ys2); \
            } } } while (0)
        ACC(0, ja.x, va.x); ACC(1, ja.y, va.y); ACC(2, ja.z, va.z); ACC(3, ja.w, va.w);
        ACC(4, jb.x, vb.x); ACC(5, jb.y, vb.y); ACC(6, jb.z, vb.z); ACC(7, jb.w, vb.w);
#undef ACC
        #pragma unroll
        for (int k = 0; k < NMOM; ++k) {
            #pragma unroll
            for (int off = 32; off; off >>= 1) m[k] += __shfl_xor(m[k], off);
        }
        if (t == 0) {
            float* dst = momp + (size_t)blockIdx.x * 64;
            #pragma unroll
            for (int k = 0; k < NMOM; ++k) dst[k] = m[k];
        }
    }
    __threadfence();
    __syncthreads();
    if (t == 0) slast = (atomicAdd(ticket, 1) == NROWBLK - 1) ? 1 : 0;
    __syncthreads();
    if (!slast) return;
    __threadfence();
    ph_tail(Kmat, momp, out, t);
}

extern "C" void kernel_launch(void* const* d_in, const int* in_sizes, int n_in,
                              void* d_out, int out_size, void* d_ws, size_t ws_size,
                              hipStream_t stream)
{
    const float* P = (const float*)d_in[0];
    const float* K = (const float*)d_in[1];
    float* out = (float*)d_out;

    float* fws    = (float*)d_ws;
    float* tr     = fws;                           // N
    float* tc     = tr + NPV;                      // N
    float* roww   = tc + NPV;                      // 8N
    int*   rowj   = (int*)(roww + 8 * NPV);        // 8N
    int*   rowcnt = rowj + 8 * NPV;                // N
    float* momp   = (float*)(rowcnt + NPV);        // 48*64
    int*   ticket = (int*)(momp + NROWBLK * 64);   // 16 ints pad
    float4* part  = (float4*)(ticket + 16);        // N*nseg float4 (offset 245824 B, 16B-aligned)

    size_t fixed_bytes = ((size_t)NPV * 19 + NROWBLK * 64 + 16) * sizeof(float);
    int nseg = 16;
    for (int cand = 128; cand >= 16; cand >>= 1) {
        if (ws_size >= fixed_bytes + (size_t)cand * NPV * sizeof(float4)) { nseg = cand; break; }
    }
    int segrows = NPV / nseg;

    k_row_top3<<<NPV / 4, 256, 0, stream>>>(P, tr, rowcnt);
    dim3 g2(NPV / 256, nseg);
    k_col_pass<<<g2, 256, 0, stream>>>(P, tr, part, segrows, rowcnt, rowj, roww);
    switch (nseg) {
        case 128: k_col_merge<128><<<NPV / 16, 256, 0, stream>>>(part, tc, ticket); break;
        case 64:  k_col_merge<64><<<NPV / 16, 256, 0, stream>>>(part, tc, ticket); break;
        case 32:  k_col_merge<32><<<NPV / 16, 256, 0, stream>>>(part, tc, ticket); break;
        default:  k_col_merge<16><<<NPV / 16, 256, 0, stream>>>(part, tc, ticket); break;
    }
    k_moments_tail<<<NROWBLK, 128, 0, stream>>>(K, tc, rowcnt, rowj, roww, momp, ticket, out);
}